// Round 2
// baseline (154.561 us; speedup 1.0000x reference)
//
#include <hip/hip_runtime.h>
#include <hip/hip_bf16.h>
#include <stdint.h>

#define G1CAST(p) ((const __attribute__((address_space(1))) void*)(p))
#define L3CAST(p) ((__attribute__((address_space(3))) void*)(p))

typedef short bf16x8 __attribute__((ext_vector_type(8)));
typedef float f32x16 __attribute__((ext_vector_type(16)));

static __device__ __forceinline__ short f2bf(float f) {
    __hip_bfloat16 b = __float2bfloat16(f);
    return __builtin_bit_cast(short, b);
}

// ---------------------------------------------------------------------------
// Kernel 1: relayout+convert weights to bf16.
// W_cat[n][gate][j][kk], kk in [0,1024): kk<512 -> W_ih[n][gate*512+j][kk]
//                                        kk>=512 -> W_hh[n][gate*512+j][kk-512]
// ---------------------------------------------------------------------------
__global__ __launch_bounds__(256) void wconv_kernel(const float* __restrict__ Wih,
                                                    const float* __restrict__ Whh,
                                                    short* __restrict__ Wcat) {
    const int tid = blockIdx.x * 256 + threadIdx.x;   // 1,572,864 threads
    const int64_t e = (int64_t)tid * 8;               // 8 elems / thread
    const int kk = (int)(e & 1023);
    const int row = (int)(e >> 10);                   // n*1536 + (gate*512+j)
    const int n = row / 1536;
    const int gr = row - n * 1536;
    const float* src = (kk < 512)
        ? Wih + ((int64_t)n * 786432 + (int64_t)gr * 512 + kk)
        : Whh + ((int64_t)n * 786432 + (int64_t)gr * 512 + (kk - 512));
    const float4 a = ((const float4*)src)[0];
    const float4 b = ((const float4*)src)[1];
    bf16x8 o;
    o[0] = f2bf(a.x); o[1] = f2bf(a.y); o[2] = f2bf(a.z); o[3] = f2bf(a.w);
    o[4] = f2bf(b.x); o[5] = f2bf(b.y); o[6] = f2bf(b.z); o[7] = f2bf(b.w);
    *(bf16x8*)(Wcat + e) = o;
}

// ---------------------------------------------------------------------------
// Kernel 2: fused block-diagonal GRU.
// Tile: BM=128 x BN=64, BK=32, 4 waves (2m x 2n), wave tile 64x32 via
// mfma_f32_32x32x16_bf16 (m_rep=2). 38.4 FLOP/LDS-byte.
// Grid 512: nblk = wgid&7 (XCD-local weights), then bt major / jt minor.
// ---------------------------------------------------------------------------
#define KS_TOTAL 32

__global__ __launch_bounds__(256, 2) void gru_kernel(
    const float* __restrict__ x, const float* __restrict__ hst,
    const short* __restrict__ Wcat,
    const float* __restrict__ b_ih, const float* __restrict__ b_hh,
    float* __restrict__ out)
{
    __shared__ short ldsA[2][128 * 32];       // 2 x 8 KB   [row][kk] swizzled
    __shared__ short ldsB[2][3 * 64 * 32];    // 2 x 12 KB  [gate][j][kk] swizzled

    const int tid = threadIdx.x;
    const int nblk = blockIdx.x & 7;          // XCD-local block index
    const int r = blockIdx.x >> 3;            // 0..63 within XCD
    const int bt = r >> 3;                    // batch tile 0..7 (slow)
    const int jt = r & 7;                     // j tile 0..7 (fast -> A L2 reuse)
    const int j0b = jt * 64;
    const int brow0 = bt * 128;

    const int lane = tid & 63;
    const int wave = tid >> 6;                // 0..3
    const int wm = wave >> 1;                 // 64-row slice
    const int wn = wave & 1;                  // 32-col slice
    const int l31 = lane & 31;
    const int k8 = lane >> 5;                 // k-half within fragment

    // ---- A staging map: thread -> (row, 16-float half) ----
    const int arow = tid >> 1;                // 0..127
    const int ahalf = tid & 1;
    const size_t a_base = (size_t)(brow0 + arow) * 4096 + (size_t)nblk * 512 + ahalf * 16;
    const int aswz = ((arow >> 1) & 3) << 4;
    const int a_ds0 = arow * 64 + ((ahalf * 32) ^ aswz);
    const int a_ds1 = arow * 64 + ((ahalf * 32 + 16) ^ aswz);

    // ---- B staging map (global_load_lds, pre-swizzled source) ----
    const int bj = tid >> 2;                  // 0..63
    const int bc4 = tid & 3;                  // 16B chunk in row
    const int bsw = (bc4 * 16) ^ (((bj >> 1) & 3) << 4);
    const size_t w_base = ((size_t)nblk * 1536 + (size_t)(j0b + bj)) * 1024 + (bsw >> 1);

    f32x16 acc_r[2] = {};
    f32x16 acc_z[2] = {};
    f32x16 acc_nx[2] = {};
    f32x16 acc_nh[2] = {};

    auto stageB = [&](int buf, int ks) {
        const short* wsrc = Wcat + w_base + ks * 32;
        char* dst = (char*)&ldsB[buf][0] + tid * 16;
        #pragma unroll
        for (int g = 0; g < 3; ++g) {
            __builtin_amdgcn_global_load_lds(G1CAST(wsrc + (size_t)g * 524288),
                                             L3CAST(dst + g * 4096), 16, 0, 0);
        }
    };

    auto computeStep = [&](int buf, f32x16 (&accN)[2]) {
        const char* Ab = (const char*)&ldsA[buf][0];
        const char* Bb = (const char*)&ldsB[buf][0];
        const int jl = wn * 32 + l31;
        const int bswz = ((jl >> 1) & 3) << 4;
        #pragma unroll
        for (int ksub = 0; ksub < 2; ++ksub) {
            const int kb = ksub * 32 + k8 * 16;
            bf16x8 af[2];
            #pragma unroll
            for (int m = 0; m < 2; ++m) {
                const int row = wm * 64 + m * 32 + l31;
                af[m] = *(const bf16x8*)(Ab + row * 64 + (kb ^ ((((row >> 1) & 3)) << 4)));
            }
            bf16x8 b0 = *(const bf16x8*)(Bb + 0 * 4096 + jl * 64 + (kb ^ bswz));
            bf16x8 b1 = *(const bf16x8*)(Bb + 1 * 4096 + jl * 64 + (kb ^ bswz));
            bf16x8 b2 = *(const bf16x8*)(Bb + 2 * 4096 + jl * 64 + (kb ^ bswz));
            #pragma unroll
            for (int m = 0; m < 2; ++m)
                acc_r[m] = __builtin_amdgcn_mfma_f32_32x32x16_bf16(af[m], b0, acc_r[m], 0, 0, 0);
            #pragma unroll
            for (int m = 0; m < 2; ++m)
                acc_z[m] = __builtin_amdgcn_mfma_f32_32x32x16_bf16(af[m], b1, acc_z[m], 0, 0, 0);
            #pragma unroll
            for (int m = 0; m < 2; ++m)
                accN[m] = __builtin_amdgcn_mfma_f32_32x32x16_bf16(af[m], b2, accN[m], 0, 0, 0);
        }
    };

    // prologue: stage ks=0 into buf 0
    {
        stageB(0, 0);
        const float4* ap = (const float4*)(x + a_base);
        float4 av0 = ap[0], av1 = ap[1], av2 = ap[2], av3 = ap[3];
        bf16x8 w0, w1;
        w0[0] = f2bf(av0.x); w0[1] = f2bf(av0.y); w0[2] = f2bf(av0.z); w0[3] = f2bf(av0.w);
        w0[4] = f2bf(av1.x); w0[5] = f2bf(av1.y); w0[6] = f2bf(av1.z); w0[7] = f2bf(av1.w);
        w1[0] = f2bf(av2.x); w1[1] = f2bf(av2.y); w1[2] = f2bf(av2.z); w1[3] = f2bf(av2.w);
        w1[4] = f2bf(av3.x); w1[5] = f2bf(av3.y); w1[6] = f2bf(av3.z); w1[7] = f2bf(av3.w);
        char* Aw = (char*)&ldsA[0][0];
        *(bf16x8*)(Aw + a_ds0) = w0;
        *(bf16x8*)(Aw + a_ds1) = w1;
        __syncthreads();
    }

    #pragma unroll 1
    for (int ks = 0; ks < KS_TOTAL; ++ks) {
        const int cur = ks & 1;
        const int nxt = cur ^ 1;
        const bool hn = (ks + 1 < KS_TOTAL);
        float4 av0, av1, av2, av3;
        if (hn) {
            stageB(nxt, ks + 1);              // async, in flight across compute
            const int ks1 = ks + 1;
            const float* asrc = (ks1 < 16) ? x : hst;
            const float4* ap = (const float4*)(asrc + a_base + (size_t)(ks1 & 15) * 32);
            av0 = ap[0]; av1 = ap[1]; av2 = ap[2]; av3 = ap[3];
        }
        if (ks < 16) computeStep(cur, acc_nx);
        else         computeStep(cur, acc_nh);
        if (hn) {                             // write-late (T14)
            bf16x8 w0, w1;
            w0[0] = f2bf(av0.x); w0[1] = f2bf(av0.y); w0[2] = f2bf(av0.z); w0[3] = f2bf(av0.w);
            w0[4] = f2bf(av1.x); w0[5] = f2bf(av1.y); w0[6] = f2bf(av1.z); w0[7] = f2bf(av1.w);
            w1[0] = f2bf(av2.x); w1[1] = f2bf(av2.y); w1[2] = f2bf(av2.z); w1[3] = f2bf(av2.w);
            w1[4] = f2bf(av3.x); w1[5] = f2bf(av3.y); w1[6] = f2bf(av3.z); w1[7] = f2bf(av3.w);
            char* Aw = (char*)&ldsA[nxt][0];
            *(bf16x8*)(Aw + a_ds0) = w0;
            *(bf16x8*)(Aw + a_ds1) = w1;
        }
        __syncthreads();                      // drains vmcnt (B) + lgkm (A writes)
    }

    // ---- epilogue: gates + output ----
    const int jb = j0b + wn * 32 + l31;       // [0,512)
    const int bb = nblk * 1536 + jb;
    const float br = b_ih[bb] + b_hh[bb];
    const float bz = b_ih[bb + 512] + b_hh[bb + 512];
    const float bnx = b_ih[bb + 1024];
    const float bnh = b_hh[bb + 1024];
    const int gcol = nblk * 512 + jb;
    #pragma unroll
    for (int m = 0; m < 2; ++m) {
        #pragma unroll
        for (int rr = 0; rr < 16; ++rr) {
            const int rowl = (rr & 3) + 8 * (rr >> 2) + 4 * k8;
            const int row = brow0 + wm * 64 + m * 32 + rowl;
            const size_t idx = (size_t)row * 4096 + gcol;
            const float sr = acc_r[m][rr] + br;
            const float sz = acc_z[m][rr] + bz;
            const float rg = 1.f / (1.f + __expf(-sr));
            const float zg = 1.f / (1.f + __expf(-sz));
            const float tin = (acc_nx[m][rr] + bnx) + rg * (acc_nh[m][rr] + bnh);
            const float e2 = __expf(-2.f * tin);
            const float ng = 2.f / (1.f + e2) - 1.f;
            const float hv = hst[idx];
            out[idx] = ng + zg * (hv - ng);
        }
    }
}

extern "C" void kernel_launch(void* const* d_in, const int* in_sizes, int n_in,
                              void* d_out, int out_size, void* d_ws, size_t ws_size,
                              hipStream_t stream) {
    (void)in_sizes; (void)n_in; (void)out_size; (void)ws_size;
    const float* x    = (const float*)d_in[0];
    const float* h    = (const float*)d_in[1];
    const float* W_ih = (const float*)d_in[2];
    const float* W_hh = (const float*)d_in[3];
    const float* b_ih = (const float*)d_in[4];
    const float* b_hh = (const float*)d_in[5];
    short* Wcat = (short*)d_ws;               // 8*3*512*1024 bf16 = 24 MB

    wconv_kernel<<<6144, 256, 0, stream>>>(W_ih, W_hh, Wcat);
    gru_kernel<<<512, 256, 0, stream>>>(x, h, Wcat, b_ih, b_hh, (float*)d_out);
}

// Round 3
// 139.081 us; speedup vs baseline: 1.1113x; 1.1113x over previous
//
#include <hip/hip_runtime.h>
#include <hip/hip_bf16.h>
#include <stdint.h>

#define G1CAST(p) ((const __attribute__((address_space(1))) void*)(p))
#define L3CAST(p) ((__attribute__((address_space(3))) void*)(p))

typedef short bf16x8 __attribute__((ext_vector_type(8)));
typedef float f32x16 __attribute__((ext_vector_type(16)));

static __device__ __forceinline__ short f2bf(float f) {
    __hip_bfloat16 b = __float2bfloat16(f);
    return __builtin_bit_cast(short, b);
}

// ---------------------------------------------------------------------------
// Kernel 1: relayout+convert weights to bf16.
// W_cat[n][gate][j][kk], kk in [0,1024): kk<512 -> W_ih[n][gate*512+j][kk]
//                                        kk>=512 -> W_hh[n][gate*512+j][kk-512]
// ---------------------------------------------------------------------------
__global__ __launch_bounds__(256) void wconv_kernel(const float* __restrict__ Wih,
                                                    const float* __restrict__ Whh,
                                                    short* __restrict__ Wcat) {
    const int tid = blockIdx.x * 256 + threadIdx.x;
    const int64_t e = (int64_t)tid * 8;
    const int kk = (int)(e & 1023);
    const int row = (int)(e >> 10);
    const int n = row / 1536;
    const int gr = row - n * 1536;
    const float* src = (kk < 512)
        ? Wih + ((int64_t)n * 786432 + (int64_t)gr * 512 + kk)
        : Whh + ((int64_t)n * 786432 + (int64_t)gr * 512 + (kk - 512));
    const float4 a = ((const float4*)src)[0];
    const float4 b = ((const float4*)src)[1];
    bf16x8 o;
    o[0] = f2bf(a.x); o[1] = f2bf(a.y); o[2] = f2bf(a.z); o[3] = f2bf(a.w);
    o[4] = f2bf(b.x); o[5] = f2bf(b.y); o[6] = f2bf(b.z); o[7] = f2bf(b.w);
    *(bf16x8*)(Wcat + e) = o;
}

// ---------------------------------------------------------------------------
// Kernel 1b: convert x,h -> bf16 pre-swizzled LDS images.
// Image tile (bt,nblk,ks) = 8 KB: [r 0..127][chunk c swizzled c^((r>>1)&3)][16B]
// ks<16 -> x k-slice ks, ks>=16 -> h k-slice ks-16.
// ---------------------------------------------------------------------------
__global__ __launch_bounds__(256) void aconv_kernel(const float* __restrict__ x,
                                                    const float* __restrict__ h,
                                                    short* __restrict__ Aimg) {
    const int gid = blockIdx.x * 256 + threadIdx.x;   // 1,048,576 threads
    const int q = gid & 511;
    const int tile = gid >> 9;                        // 0..2047
    const int c4 = q & 3;
    const int r = q >> 2;                             // 0..127
    const int ks = tile & 31;
    const int nblk = (tile >> 5) & 7;
    const int bt = tile >> 8;
    const float* base = (ks < 16) ? x : h;
    const float* src = base + ((size_t)(bt * 128 + r) * 4096
                               + nblk * 512 + (ks & 15) * 32 + c4 * 8);
    const float4 a = ((const float4*)src)[0];
    const float4 b = ((const float4*)src)[1];
    bf16x8 o;
    o[0] = f2bf(a.x); o[1] = f2bf(a.y); o[2] = f2bf(a.z); o[3] = f2bf(a.w);
    o[4] = f2bf(b.x); o[5] = f2bf(b.y); o[6] = f2bf(b.z); o[7] = f2bf(b.w);
    *(bf16x8*)(Aimg + (size_t)tile * 4096 + r * 32 + ((c4 ^ ((r >> 1) & 3)) * 8)) = o;
}

// ---------------------------------------------------------------------------
// Kernel 2: fused block-diagonal GRU. BM=128 x BN=64, BK=32, 4 waves,
// wave tile 64x32 via mfma_f32_32x32x16_bf16. All staging via
// global_load_lds — zero registers staged across the MFMA block.
// ---------------------------------------------------------------------------
#define KS_TOTAL 32

__global__ __launch_bounds__(256, 2) void gru_kernel(
    const float* __restrict__ hst,
    const short* __restrict__ Wcat, const short* __restrict__ Aimg,
    const float* __restrict__ b_ih, const float* __restrict__ b_hh,
    float* __restrict__ out)
{
    __shared__ short ldsA[2][128 * 32];       // 2 x 8 KB
    __shared__ short ldsB[2][3 * 64 * 32];    // 2 x 12 KB

    const int tid = threadIdx.x;
    const int nblk = blockIdx.x & 7;          // XCD-local block index
    const int r = blockIdx.x >> 3;
    const int bt = r >> 3;                    // batch tile (slow)
    const int jt = r & 7;                     // j tile (fast)
    const int j0b = jt * 64;
    const int brow0 = bt * 128;

    const int lane = tid & 63;
    const int wave = tid >> 6;
    const int wm = wave >> 1;
    const int wn = wave & 1;
    const int l31 = lane & 31;
    const int k8 = lane >> 5;

    const int bj = tid >> 2;
    const int bc4 = tid & 3;
    const int bsw = (bc4 * 16) ^ (((bj >> 1) & 3) << 4);
    const size_t w_base = ((size_t)nblk * 1536 + (size_t)(j0b + bj)) * 1024 + (bsw >> 1);
    const size_t a_tile0 = ((size_t)(bt * 8 + nblk) * 32) << 13;   // byte offset of tile (.,.,ks=0)

    f32x16 acc_r[2] = {};
    f32x16 acc_z[2] = {};
    f32x16 acc_nx[2] = {};
    f32x16 acc_nh[2] = {};

    auto stageB = [&](int buf, int ks) {
        const short* wsrc = Wcat + w_base + ks * 32;
        char* dst = (char*)&ldsB[buf][0] + tid * 16;
        #pragma unroll
        for (int g = 0; g < 3; ++g) {
            __builtin_amdgcn_global_load_lds(G1CAST(wsrc + (size_t)g * 524288),
                                             L3CAST(dst + g * 4096), 16, 0, 0);
        }
    };
    auto stageA = [&](int buf, int ks) {
        const char* asrc = (const char*)Aimg + a_tile0 + ((size_t)ks << 13) + tid * 16;
        char* dst = (char*)&ldsA[buf][0] + tid * 16;
        __builtin_amdgcn_global_load_lds(G1CAST(asrc), L3CAST(dst), 16, 0, 0);
        __builtin_amdgcn_global_load_lds(G1CAST(asrc + 4096), L3CAST(dst + 4096), 16, 0, 0);
    };

    auto computeStep = [&](int buf, f32x16 (&accN)[2]) {
        const char* Ab = (const char*)&ldsA[buf][0];
        const char* Bb = (const char*)&ldsB[buf][0];
        const int jl = wn * 32 + l31;
        const int bswz = ((jl >> 1) & 3) << 4;
        #pragma unroll
        for (int ksub = 0; ksub < 2; ++ksub) {
            const int kb = ksub * 32 + k8 * 16;
            bf16x8 af[2];
            #pragma unroll
            for (int m = 0; m < 2; ++m) {
                const int row = wm * 64 + m * 32 + l31;
                af[m] = *(const bf16x8*)(Ab + row * 64 + (kb ^ ((((row >> 1) & 3)) << 4)));
            }
            bf16x8 b0 = *(const bf16x8*)(Bb + 0 * 4096 + jl * 64 + (kb ^ bswz));
            bf16x8 b1 = *(const bf16x8*)(Bb + 1 * 4096 + jl * 64 + (kb ^ bswz));
            bf16x8 b2 = *(const bf16x8*)(Bb + 2 * 4096 + jl * 64 + (kb ^ bswz));
            #pragma unroll
            for (int m = 0; m < 2; ++m)
                acc_r[m] = __builtin_amdgcn_mfma_f32_32x32x16_bf16(af[m], b0, acc_r[m], 0, 0, 0);
            #pragma unroll
            for (int m = 0; m < 2; ++m)
                acc_z[m] = __builtin_amdgcn_mfma_f32_32x32x16_bf16(af[m], b1, acc_z[m], 0, 0, 0);
            #pragma unroll
            for (int m = 0; m < 2; ++m)
                accN[m] = __builtin_amdgcn_mfma_f32_32x32x16_bf16(af[m], b2, accN[m], 0, 0, 0);
        }
    };

    stageA(0, 0);
    stageB(0, 0);
    __syncthreads();

    #pragma unroll 1
    for (int ks = 0; ks < KS_TOTAL; ++ks) {
        const int cur = ks & 1;
        const int nxt = cur ^ 1;
        if (ks + 1 < KS_TOTAL) {
            stageB(nxt, ks + 1);
            stageA(nxt, ks + 1);
        }
        if (ks < 16) computeStep(cur, acc_nx);
        else         computeStep(cur, acc_nh);
        __syncthreads();
    }

    const int jb = j0b + wn * 32 + l31;
    const int bb = nblk * 1536 + jb;
    const float br = b_ih[bb] + b_hh[bb];
    const float bz = b_ih[bb + 512] + b_hh[bb + 512];
    const float bnx = b_ih[bb + 1024];
    const float bnh = b_hh[bb + 1024];
    const int gcol = nblk * 512 + jb;
    #pragma unroll
    for (int m = 0; m < 2; ++m) {
        #pragma unroll
        for (int rr = 0; rr < 16; ++rr) {
            const int rowl = (rr & 3) + 8 * (rr >> 2) + 4 * k8;
            const int row = brow0 + wm * 64 + m * 32 + rowl;
            const size_t idx = (size_t)row * 4096 + gcol;
            const float sr = acc_r[m][rr] + br;
            const float sz = acc_z[m][rr] + bz;
            const float rg = 1.f / (1.f + __expf(-sr));
            const float zg = 1.f / (1.f + __expf(-sz));
            const float tin = (acc_nx[m][rr] + bnx) + rg * (acc_nh[m][rr] + bnh);
            const float e2 = __expf(-2.f * tin);
            const float ng = 2.f / (1.f + e2) - 1.f;
            const float hv = hst[idx];
            out[idx] = ng + zg * (hv - ng);
        }
    }
}

extern "C" void kernel_launch(void* const* d_in, const int* in_sizes, int n_in,
                              void* d_out, int out_size, void* d_ws, size_t ws_size,
                              hipStream_t stream) {
    (void)in_sizes; (void)n_in; (void)out_size; (void)ws_size;
    const float* x    = (const float*)d_in[0];
    const float* h    = (const float*)d_in[1];
    const float* W_ih = (const float*)d_in[2];
    const float* W_hh = (const float*)d_in[3];
    const float* b_ih = (const float*)d_in[4];
    const float* b_hh = (const float*)d_in[5];
    short* Wcat = (short*)d_ws;                              // 24 MB
    short* Aimg = (short*)d_ws + (size_t)12 * 1024 * 1024;   // 16 MB

    wconv_kernel<<<6144, 256, 0, stream>>>(W_ih, W_hh, Wcat);
    aconv_kernel<<<4096, 256, 0, stream>>>(x, h, Aimg);
    gru_kernel<<<512, 256, 0, stream>>>(h, Wcat, Aimg, b_ih, b_hh, (float*)d_out);
}

// Round 4
// 61.015 us; speedup vs baseline: 2.5332x; 2.2795x over previous
//
#include <hip/hip_runtime.h>
#include <hip/hip_bf16.h>
#include <stdint.h>

#define G1CAST(p) ((const __attribute__((address_space(1))) void*)(p))
#define L3CAST(p) ((__attribute__((address_space(3))) void*)(p))

typedef short bf16x8 __attribute__((ext_vector_type(8)));
typedef float f32x16 __attribute__((ext_vector_type(16)));

static __device__ __forceinline__ short f2bf(float f) {
    __hip_bfloat16 b = __float2bfloat16(f);
    return __builtin_bit_cast(short, b);
}

// ---------------------------------------------------------------------------
// Kernel 1: relayout+convert weights to bf16 (linear image).
// W_cat[n][gate][j][kk], kk in [0,1024): kk<512 -> W_ih[n][gate*512+j][kk]
//                                        kk>=512 -> W_hh[n][gate*512+j][kk-512]
// ---------------------------------------------------------------------------
__global__ __launch_bounds__(256) void wconv_kernel(const float* __restrict__ Wih,
                                                    const float* __restrict__ Whh,
                                                    short* __restrict__ Wcat) {
    const int tid = blockIdx.x * 256 + threadIdx.x;
    const int64_t e = (int64_t)tid * 8;
    const int kk = (int)(e & 1023);
    const int row = (int)(e >> 10);
    const int n = row / 1536;
    const int gr = row - n * 1536;
    const float* src = (kk < 512)
        ? Wih + ((int64_t)n * 786432 + (int64_t)gr * 512 + kk)
        : Whh + ((int64_t)n * 786432 + (int64_t)gr * 512 + (kk - 512));
    const float4 a = ((const float4*)src)[0];
    const float4 b = ((const float4*)src)[1];
    bf16x8 o;
    o[0] = f2bf(a.x); o[1] = f2bf(a.y); o[2] = f2bf(a.z); o[3] = f2bf(a.w);
    o[4] = f2bf(b.x); o[5] = f2bf(b.y); o[6] = f2bf(b.z); o[7] = f2bf(b.w);
    *(bf16x8*)(Wcat + e) = o;
}

// ---------------------------------------------------------------------------
// Kernel 1b: convert x,h -> bf16 pre-swizzled LDS images.
// Image tile (bt,nblk,ks) = 8 KB: [r 0..127][chunk c at pos c^((r>>1)&3)][16B]
// ks<16 -> x k-slice ks, ks>=16 -> h k-slice ks-16.
// ---------------------------------------------------------------------------
__global__ __launch_bounds__(256) void aconv_kernel(const float* __restrict__ x,
                                                    const float* __restrict__ h,
                                                    short* __restrict__ Aimg) {
    const int gid = blockIdx.x * 256 + threadIdx.x;   // 1,048,576 threads
    const int q = gid & 511;
    const int tile = gid >> 9;                        // 0..2047
    const int c4 = q & 3;
    const int r = q >> 2;                             // 0..127
    const int ks = tile & 31;
    const int nblk = (tile >> 5) & 7;
    const int bt = tile >> 8;
    const float* base = (ks < 16) ? x : h;
    const float* src = base + ((size_t)(bt * 128 + r) * 4096
                               + nblk * 512 + (ks & 15) * 32 + c4 * 8);
    const float4 a = ((const float4*)src)[0];
    const float4 b = ((const float4*)src)[1];
    bf16x8 o;
    o[0] = f2bf(a.x); o[1] = f2bf(a.y); o[2] = f2bf(a.z); o[3] = f2bf(a.w);
    o[4] = f2bf(b.x); o[5] = f2bf(b.y); o[6] = f2bf(b.z); o[7] = f2bf(b.w);
    *(bf16x8*)(Aimg + (size_t)tile * 4096 + r * 32 + ((c4 ^ ((r >> 1) & 3)) * 8)) = o;
}

// ---------------------------------------------------------------------------
// Kernel 2: fused block-diagonal GRU.
// BM=128 x BN=64, BK=32, 512 threads = 8 waves (4m x 2n), wave tile 32x32.
// acc = 4 x f32x16 = 64 regs/lane. Ring-4 LDS, stage-ahead-3, counted vmcnt.
// ---------------------------------------------------------------------------
__global__ __launch_bounds__(512, 4) void gru_kernel(
    const float* __restrict__ hst,
    const short* __restrict__ Wcat, const short* __restrict__ Aimg,
    const float* __restrict__ b_ih, const float* __restrict__ b_hh,
    float* __restrict__ out)
{
    __shared__ short ldsA[4][128 * 32];       // 4 x 8 KB
    __shared__ short ldsB[4][3 * 64 * 32];    // 4 x 12 KB   (80 KB total)

    const int tid = threadIdx.x;
    const int nblk = blockIdx.x & 7;          // XCD-local weight slice
    const int rr_ = blockIdx.x >> 3;
    const int bt = rr_ >> 3;                  // batch tile (slow)
    const int jt = rr_ & 7;                   // j tile (fast -> A L2 reuse)
    const int j0b = jt * 64;
    const int brow0 = bt * 128;

    const int lane = tid & 63;
    const int wave = tid >> 6;                // 0..7
    const int wm = wave >> 1;                 // 0..3 (32-row slice)
    const int wn = wave & 1;                  // 0..1 (32-col slice)
    const int l31 = lane & 31;
    const int k8 = lane >> 5;

    // B staging map: chunk c=tid -> gate=tid>>8, j=(tid&255)>>2, cir=tid&3
    const int bj  = (tid & 255) >> 2;
    const int cir = tid & 3;
    const int g1  = tid >> 8;                 // 0 or 1
    const size_t bsrc1 = ((size_t)nblk * 1536 + (size_t)g1 * 512 + (size_t)(j0b + bj)) * 1024
                       + (size_t)((cir ^ ((bj >> 1) & 3)) * 8);
    const size_t bsrc2 = bsrc1 + (size_t)2 * 512 * 1024;   // gate 2 (valid when tid<256, g1==0)
    const size_t a_tile0 = ((size_t)(bt * 8 + nblk) * 32) << 13;

    f32x16 acc_r = {};
    f32x16 acc_z = {};
    f32x16 acc_nx = {};
    f32x16 acc_nh = {};

    auto stage = [&](int buf, int ks) {
        const char* asrc = (const char*)Aimg + a_tile0 + ((size_t)ks << 13) + (size_t)tid * 16;
        __builtin_amdgcn_global_load_lds(G1CAST(asrc),
                                         L3CAST((char*)&ldsA[buf][0] + tid * 16), 16, 0, 0);
        const short* ws = Wcat + (size_t)ks * 32;
        __builtin_amdgcn_global_load_lds(G1CAST(ws + bsrc1),
                                         L3CAST((char*)&ldsB[buf][0] + tid * 16), 16, 0, 0);
        if (tid < 256)   // wave-uniform (waves 0..3)
            __builtin_amdgcn_global_load_lds(G1CAST(ws + bsrc2),
                                             L3CAST((char*)&ldsB[buf][0] + 8192 + tid * 16), 16, 0, 0);
    };

    const int arow = wm * 32 + l31;
    const int aoff = arow * 64;
    const int aswz = ((arow >> 1) & 3) << 4;
    const int jl = wn * 32 + l31;
    const int boff = jl * 64;
    const int bswz = ((jl >> 1) & 3) << 4;

    auto computeStep = [&](const short* Ab_s, const short* Bb_s, f32x16& accN) {
        const char* Ab = (const char*)Ab_s;
        const char* Bb = (const char*)Bb_s;
        #pragma unroll
        for (int ksub = 0; ksub < 2; ++ksub) {
            const int kb = ksub * 32 + k8 * 16;
            bf16x8 af = *(const bf16x8*)(Ab + aoff + (kb ^ aswz));
            bf16x8 b0 = *(const bf16x8*)(Bb + 0 * 4096 + boff + (kb ^ bswz));
            bf16x8 b1 = *(const bf16x8*)(Bb + 1 * 4096 + boff + (kb ^ bswz));
            bf16x8 b2 = *(const bf16x8*)(Bb + 2 * 4096 + boff + (kb ^ bswz));
            acc_r = __builtin_amdgcn_mfma_f32_32x32x16_bf16(af, b0, acc_r, 0, 0, 0);
            acc_z = __builtin_amdgcn_mfma_f32_32x32x16_bf16(af, b1, acc_z, 0, 0, 0);
            accN  = __builtin_amdgcn_mfma_f32_32x32x16_bf16(af, b2, accN, 0, 0, 0);
        }
    };

    // prologue: fill ring slots 0,1,2
    stage(0, 0); stage(1, 1); stage(2, 2);

    // main pipeline: one barrier + counted vmcnt per iteration (never 0)
    #pragma unroll 1
    for (int i = 0; i < 16; ++i) {
        asm volatile("s_waitcnt vmcnt(4)" ::: "memory");   // stage(i) landed (FIFO)
        __builtin_amdgcn_s_barrier();
        stage((i + 3) & 3, i + 3);
        computeStep(ldsA[i & 3], ldsB[i & 3], acc_nx);
    }
    #pragma unroll 1
    for (int i = 16; i < 29; ++i) {
        asm volatile("s_waitcnt vmcnt(4)" ::: "memory");
        __builtin_amdgcn_s_barrier();
        stage((i + 3) & 3, i + 3);
        computeStep(ldsA[i & 3], ldsB[i & 3], acc_nh);
    }
    // i=29 (no stage left; 30,31 outstanding)
    asm volatile("s_waitcnt vmcnt(4)" ::: "memory");
    __builtin_amdgcn_s_barrier();
    computeStep(ldsA[29 & 3], ldsB[29 & 3], acc_nh);
    // i=30
    asm volatile("s_waitcnt vmcnt(2)" ::: "memory");
    __builtin_amdgcn_s_barrier();
    computeStep(ldsA[30 & 3], ldsB[30 & 3], acc_nh);
    // i=31
    asm volatile("s_waitcnt vmcnt(0)" ::: "memory");
    __builtin_amdgcn_s_barrier();
    computeStep(ldsA[31 & 3], ldsB[31 & 3], acc_nh);

    // ---- epilogue: gates + output (wave owns 32x32 tile) ----
    const int jb = j0b + wn * 32 + l31;       // [0,512)
    const int bb = nblk * 1536 + jb;
    const float br = b_ih[bb] + b_hh[bb];
    const float bz = b_ih[bb + 512] + b_hh[bb + 512];
    const float bnx = b_ih[bb + 1024];
    const float bnh = b_hh[bb + 1024];
    const int gcol = nblk * 512 + jb;
    #pragma unroll
    for (int rr = 0; rr < 16; ++rr) {
        const int rowl = (rr & 3) + 8 * (rr >> 2) + 4 * k8;
        const int row = brow0 + wm * 32 + rowl;
        const size_t idx = (size_t)row * 4096 + gcol;
        const float sr = acc_r[rr] + br;
        const float sz = acc_z[rr] + bz;
        const float rg = 1.f / (1.f + __expf(-sr));
        const float zg = 1.f / (1.f + __expf(-sz));
        const float tin = (acc_nx[rr] + bnx) + rg * (acc_nh[rr] + bnh);
        const float e2 = __expf(-2.f * tin);
        const float ng = 2.f / (1.f + e2) - 1.f;
        const float hv = hst[idx];
        out[idx] = ng + zg * (hv - ng);
    }
}

extern "C" void kernel_launch(void* const* d_in, const int* in_sizes, int n_in,
                              void* d_out, int out_size, void* d_ws, size_t ws_size,
                              hipStream_t stream) {
    (void)in_sizes; (void)n_in; (void)out_size; (void)ws_size;
    const float* x    = (const float*)d_in[0];
    const float* h    = (const float*)d_in[1];
    const float* W_ih = (const float*)d_in[2];
    const float* W_hh = (const float*)d_in[3];
    const float* b_ih = (const float*)d_in[4];
    const float* b_hh = (const float*)d_in[5];
    short* Wcat = (short*)d_ws;                              // 24 MB
    short* Aimg = (short*)d_ws + (size_t)12 * 1024 * 1024;   // 16 MB

    wconv_kernel<<<6144, 256, 0, stream>>>(W_ih, W_hh, Wcat);
    aconv_kernel<<<4096, 256, 0, stream>>>(x, h, Aimg);
    gru_kernel<<<512, 512, 0, stream>>>(h, Wcat, Aimg, b_ih, b_hh, (float*)d_out);
}